// Round 8
// baseline (759.060 us; speedup 1.0000x reference)
//
#include <hip/hip_runtime.h>
#include <stdint.h>

#define AS1 __attribute__((address_space(1)))
#define AS3 __attribute__((address_space(3)))

typedef _Float16 f16x8 __attribute__((ext_vector_type(8)));
typedef float f32x4 __attribute__((ext_vector_type(4)));

__device__ __forceinline__ unsigned short f32_f16(float f) {
  union { _Float16 h; unsigned short u; } v; v.h = (_Float16)f; return v.u;
}
__device__ __forceinline__ float f16_f32(unsigned short u) {
  union { _Float16 h; unsigned short u; } v; v.u = u; return (float)v.h;
}
// plain staging (L1+L2 cached) — for the GEMM
__device__ __forceinline__ void gl_lds16(const unsigned short* g, unsigned short* l) {
  __builtin_amdgcn_global_load_lds((const AS1 unsigned int*)g, (AS3 unsigned int*)l, 16, 0, 0);
}
// coherent staging — bypass L1+L2, read the Infinity Cache (R6-proven)
__device__ __forceinline__ void gl_lds16_coh(const unsigned short* g, unsigned short* l) {
  __builtin_amdgcn_global_load_lds((const AS1 unsigned int*)g, (AS3 unsigned int*)l, 16, 0, 17);
}

// ---------------- fused f32 -> fp16 conversion (facts, Wr, W, mem_old) ----------
__global__ void cvt_all(const float4* __restrict__ sf, ushort4* __restrict__ df,
                        const float4* __restrict__ s1, ushort4* __restrict__ d1,
                        const float4* __restrict__ s2, ushort4* __restrict__ d2,
                        const float4* __restrict__ sm, ushort4* __restrict__ dm) {
  int i = blockIdx.x * blockDim.x + threadIdx.x;
  int st = gridDim.x * blockDim.x;
  for (int k = i; k < 4751360; k += st) {
    const float4* s; ushort4* d; int off;
    if (k < 4194304)      { s = sf; d = df; off = k; }
    else if (k < 4456448) { s = s1; d = d1; off = k - 4194304; }
    else if (k < 4718592) { s = s2; d = d2; off = k - 4456448; }
    else                  { s = sm; d = dm; off = k - 4718592; }
    float4 v = s[off];
    ushort4 o;
    o.x = f32_f16(v.x); o.y = f32_f16(v.y); o.z = f32_f16(v.z); o.w = f32_f16(v.w);
    d[off] = o;
  }
}

// ---------------- phase 1: C[t][b][0:2048] = facts(b,t,:) @ [Wr|W]^T (fp16 out) ----
// BK=64: 16 K-tiles (half the barrier drains). LDS rows 128B; staging uses the
// XOR source-swizzle (LDS pos p of row r holds source chunk p^(r&7)) so the
// ds_read_b128 fragment reads spread uniformly over all 32 banks.
__global__ __launch_bounds__(256, 2) void gemm_fw(
    const unsigned short* __restrict__ A,
    const unsigned short* __restrict__ Bt,
    unsigned short* __restrict__ Ct)
{
  __shared__ __align__(16) unsigned short As[128 * 64];
  __shared__ __align__(16) unsigned short Bs[128 * 64];
  const int tid = threadIdx.x;
  const int lane = tid & 63;
  const int wv = tid >> 6;
  const int q = lane >> 4, ln = lane & 15;
  const int bm = blockIdx.x, bn = blockIdx.y;
  const int wm = (wv >> 1) * 64, wn = (wv & 1) * 64;

  f32x4 acc[4][4] = {};

  for (int kt = 0; kt < 1024; kt += 64) {
    __syncthreads();
#pragma unroll
    for (int rr = 0; rr < 4; ++rr) {
      int chunk = rr * 256 + tid;          // 0..1023
      int r = chunk >> 3, c = chunk & 7;   // 8 chunks (16B) per 128B row
      int cs = c ^ (r & 7);                // source chunk for this LDS pos
      gl_lds16(A + (size_t)(bm * 128 + r) * 1024 + kt + cs * 8, As + chunk * 8);
      gl_lds16(Bt + (size_t)(bn * 128 + r) * 1024 + kt + cs * 8, Bs + chunk * 8);
    }
    __syncthreads();
    f16x8 af[4][2], bfr[4][2];
#pragma unroll
    for (int mi = 0; mi < 4; ++mi)
#pragma unroll
      for (int kk = 0; kk < 2; ++kk)
        af[mi][kk] = *(const f16x8*)(As + (wm + mi * 16 + ln) * 64 + (((q + 4 * kk) ^ (ln & 7)) * 8));
#pragma unroll
    for (int ni = 0; ni < 4; ++ni)
#pragma unroll
      for (int kk = 0; kk < 2; ++kk)
        bfr[ni][kk] = *(const f16x8*)(Bs + (wn + ni * 16 + ln) * 64 + (((q + 4 * kk) ^ (ln & 7)) * 8));
#pragma unroll
    for (int kk = 0; kk < 2; ++kk)
#pragma unroll
      for (int mi = 0; mi < 4; ++mi)
#pragma unroll
        for (int ni = 0; ni < 4; ++ni)
          acc[mi][ni] = __builtin_amdgcn_mfma_f32_16x16x32_f16(af[mi][kk], bfr[ni][kk], acc[mi][ni], 0, 0, 0);
  }
#pragma unroll
  for (int mi = 0; mi < 4; ++mi)
#pragma unroll
    for (int ni = 0; ni < 4; ++ni)
#pragma unroll
      for (int r2 = 0; r2 < 4; ++r2) {
        int trow = wm + mi * 16 + q * 4 + r2;   // == t
        int col = bn * 128 + wn + ni * 16 + ln; // 0..2047: [fWr | fW]
        Ct[(size_t)trow * 262144 + (size_t)bm * 2048 + col] = f32_f16(acc[mi][ni][r2]);
      }
}

// ---------------- phase 2: the recurrence ----------------
// Grid 256 = 8 groups x 32 dim-slices; ga = blockIdx&7 (XCD-local grouping is
// a locality heuristic only — coherence is R6's proven IC path everywhere).
// Barrier v4: 2 block-barriers/step. Per-WAVE flag release (each matrix-0 wave
// drains its own vmcnt then releases its flag: 64 flags/group, 64B apart);
// ALL waves poll all 64 flags in parallel (one lane per flag), then fall
// straight into staging (At-reuse safe: all At reads precede B2).
__global__ __launch_bounds__(256, 2) void gru_recur(
    const unsigned short* __restrict__ fwx,   // [128 t][128 b][2048] f16
    const float* __restrict__ Urw, const float* __restrict__ Urb,
    const float* __restrict__ Uw,  const float* __restrict__ Ub,
    const float* __restrict__ g,              // [128 b][128 t]
    const float* __restrict__ mem_old,        // [128][1024]
    const int* __restrict__ nfp,              // [128]
    unsigned short* __restrict__ hbf,         // [2][128][1024] f16
    unsigned int* __restrict__ flg,           // [8 ga][64 wv][16 pad] u32
    float* __restrict__ out)                  // [128][1024] f32
{
  __shared__ __align__(16) unsigned char At[32768]; // 16 rows x 2048B, dense
  __shared__ float xchg[512];

  const int tid = threadIdx.x;
  const int lane = tid & 63;
  const int w = tid >> 6;
  const int q = lane >> 4;
  const int ln = lane & 15;
  const int matrix = w >> 1;
  const int ntile = w & 1;
  const int ga = blockIdx.x & 7;    // XCD-local group under round-robin dispatch
  const int dsl = blockIdx.x >> 3;  // dim-slice within group
  const int b0 = ga * 16;
  const int n_g = dsl * 32 + ntile * 16 + ln;

  // --- one-time: weights into registers (B-fragment layout: n=lane&15, k=q*8+j) ---
  const float* Wm = matrix ? Uw : Urw;
  f16x8 bw[32];
#pragma unroll
  for (int ks = 0; ks < 32; ++ks) {
    const float* s = Wm + (size_t)n_g * 1024 + ks * 32 + q * 8;
    float4 x0 = *(const float4*)s;
    float4 x1 = *(const float4*)(s + 4);
    f16x8 t;
    t[0] = (_Float16)x0.x; t[1] = (_Float16)x0.y;
    t[2] = (_Float16)x0.z; t[3] = (_Float16)x0.w;
    t[4] = (_Float16)x1.x; t[5] = (_Float16)x1.y;
    t[6] = (_Float16)x1.z; t[7] = (_Float16)x1.w;
    bw[ks] = t;
  }
  const float bias = (matrix ? Ub : Urb)[n_g];
  f32x4 acc = {bias, bias, bias, bias};

  float h_own[4] = {0.f, 0.f, 0.f, 0.f};
  int nf[4] = {0, 0, 0, 0};
  if (matrix == 0) {
#pragma unroll
    for (int r = 0; r < 4; ++r) {
      int b = b0 + q * 4 + r;
      h_own[r] = mem_old[(size_t)b * 1024 + n_g];
      nf[r] = nfp[b];
    }
  }

  // A-fragment read bases: row ln, chunk(ks) = (q + 4*ks) ^ (ln&7).
  const int swz = ln & 7;
  const int rowb = ln * 2048 + (q ^ (swz & 3)) * 16;
  const int be = rowb + ((swz >> 2) << 6);        // ks even
  const int bo = rowb + (((swz >> 2) ^ 1) << 6);  // ks odd

  for (int t = 0; t < 128; ++t) {
    // stage h(t) group tile (16 x 1024 f16 = 32KB), coherent (IC) reads
    const unsigned short* hsrc = hbf + (size_t)(t & 1) * 131072 + (size_t)b0 * 1024;
#pragma unroll
    for (int j = 0; j < 8; ++j) {
      int blk = w * 8 + j;
      int m = blk >> 1, kh = blk & 1;
      gl_lds16_coh(hsrc + m * 1024 + kh * 512 + ((lane ^ (m & 7)) * 8),
                   (unsigned short*)(At + m * 2048 + kh * 1024));
    }
    __syncthreads(); // B1: staging drained

    // epilogue operands: issue early, consumed after MFMA loop (plain cached loads)
    float fwrv[4], fwv[4], gv[4];
    if (matrix == 0) {
#pragma unroll
      for (int r = 0; r < 4; ++r) {
        int b = b0 + q * 4 + r;
        size_t base = (size_t)t * 262144 + (size_t)b * 2048;
        fwrv[r] = f16_f32(fwx[base + n_g]);
        fwv[r]  = f16_f32(fwx[base + 1024 + n_g]);
        gv[r]   = g[b * 128 + t];
      }
    }

#pragma unroll
    for (int ks = 0; ks < 32; ++ks) {
      const unsigned char* ap = At + (((ks & 1) ? bo : be) + ((ks >> 1) << 7));
      f16x8 a = *(const f16x8*)ap;
      acc = __builtin_amdgcn_mfma_f32_16x16x32_f16(a, bw[ks], acc, 0, 0, 0);
    }

    if (matrix == 1) { // u = U h + U_b -> exchange to r-side waves
#pragma unroll
      for (int r = 0; r < 4; ++r)
        xchg[ntile * 256 + (q * 4 + r) * 16 + ln] = acc[r];
    }
    __syncthreads(); // B2: xchg visible; all At reads of step t complete
    if (matrix == 0) {
      unsigned int* hb32 = (unsigned int*)(hbf + (size_t)((t + 1) & 1) * 131072);
#pragma unroll
      for (int r = 0; r < 4; ++r) {
        float u = xchg[ntile * 256 + (q * 4 + r) * 16 + ln];
        float rg = 1.0f / (1.0f + __expf(-(acc[r] + fwrv[r])));
        float pre = fwv[r] + rg * u;
        float e2 = __expf(-2.0f * fabsf(pre));
        float th = (1.0f - e2) / (1.0f + e2);
        float ht = copysignf(th, pre);
        float hn = gv[r] * ht + (1.0f - gv[r]) * h_own[r];
        h_own[r] = hn;
        int b = b0 + q * 4 + r;
        // pack adjacent dims (n_g even|odd) into u32, write-through to IC
        unsigned short hu = f32_f16(hn);
        unsigned short pu = (unsigned short)__shfl_xor((int)hu, 1, 64);
        if (!(ln & 1))
          __hip_atomic_store(&hb32[(b * 1024 + n_g) >> 1],
                             (unsigned)hu | ((unsigned)pu << 16),
                             __ATOMIC_RELAXED, __HIP_MEMORY_SCOPE_AGENT);
        if (t == nf[r] - 1) out[(size_t)b * 1024 + n_g] = hn;
      }
      // per-wave release: this wave's h-stores are IC-acked, then flag
      if (t < 127) {
        asm volatile("s_waitcnt vmcnt(0)" ::: "memory");
        if (lane == 0)
          __hip_atomic_store(&flg[(ga * 64 + dsl * 2 + ntile) * 16],
                             (unsigned)(t + 1),
                             __ATOMIC_RELAXED, __HIP_MEMORY_SCOPE_AGENT);
      }
    }
    acc[0] = bias; acc[1] = bias; acc[2] = bias; acc[3] = bias;

    if (t < 127) {
      // all waves poll all 64 per-wave flags (one lane per flag), no barrier after
      unsigned int* fp = &flg[(ga * 64 + lane) * 16];
      for (;;) {
        unsigned v = __hip_atomic_load(fp, __ATOMIC_RELAXED, __HIP_MEMORY_SCOPE_AGENT);
        if (__ballot(v < (unsigned)(t + 1)) == 0ull) break;
      }
    }
  }
}

extern "C" void kernel_launch(void* const* d_in, const int* in_sizes, int n_in,
                              void* d_out, int out_size, void* d_ws, size_t ws_size,
                              hipStream_t stream) {
  const float* facts     = (const float*)d_in[0]; // [128][128][1024]
  const int*   num_facts = (const int*)d_in[1];   // [128]
  const float* g         = (const float*)d_in[2]; // [128][128][1]
  const float* mem_old   = (const float*)d_in[3]; // [128][1][1024]
  const float* Wr        = (const float*)d_in[4]; // [1024][1024]
  const float* Urw       = (const float*)d_in[5];
  const float* Urb       = (const float*)d_in[6];
  const float* W         = (const float*)d_in[7];
  const float* Uw        = (const float*)d_in[8];
  const float* Ub        = (const float*)d_in[9];

  // workspace layout (f16 elements unless noted)
  unsigned short* facts_h = (unsigned short*)d_ws;        // 16,777,216
  unsigned short* wstack  = facts_h + 16777216;           //  2,097,152 ([Wr|W])
  unsigned short* fwx     = wstack + 2097152;             // 33,554,432 ([t][b][2048])
  unsigned short* hbf     = fwx + 33554432;               //    262,144 (2 x [128][1024])
  unsigned int*   flg     = (unsigned int*)(hbf + 262144);// 8*64*16 u32 = 32KB
  float* out = (float*)d_out;

  hipMemsetAsync(flg, 0, 8 * 64 * 16 * 4, stream);
  cvt_all<<<4096, 256, 0, stream>>>(
      (const float4*)facts,   (ushort4*)facts_h,
      (const float4*)Wr,      (ushort4*)wstack,
      (const float4*)W,       (ushort4*)(wstack + 1048576),
      (const float4*)mem_old, (ushort4*)hbf);
  gemm_fw<<<dim3(128, 16), 256, 0, stream>>>(facts_h, wstack, fwx);
  gru_recur<<<256, 256, 0, stream>>>(fwx, Urw, Urb, Uw, Ub, g, mem_old, num_facts, hbf, flg, out);
}

// Round 9
// 630.012 us; speedup vs baseline: 1.2048x; 1.2048x over previous
//
#include <hip/hip_runtime.h>
#include <stdint.h>

#define AS1 __attribute__((address_space(1)))
#define AS3 __attribute__((address_space(3)))

typedef _Float16 f16x8 __attribute__((ext_vector_type(8)));
typedef float f32x4 __attribute__((ext_vector_type(4)));

__device__ __forceinline__ unsigned short f32_f16(float f) {
  union { _Float16 h; unsigned short u; } v; v.h = (_Float16)f; return v.u;
}
__device__ __forceinline__ float f16_f32(unsigned short u) {
  union { _Float16 h; unsigned short u; } v; v.u = u; return (float)v.h;
}
// plain staging (L1+L2 cached) — for the GEMM
__device__ __forceinline__ void gl_lds16(const unsigned short* g, unsigned short* l) {
  __builtin_amdgcn_global_load_lds((const AS1 unsigned int*)g, (AS3 unsigned int*)l, 16, 0, 0);
}
// coherent staging — bypass L1+L2, read the Infinity Cache (R6-proven)
__device__ __forceinline__ void gl_lds16_coh(const unsigned short* g, unsigned short* l) {
  __builtin_amdgcn_global_load_lds((const AS1 unsigned int*)g, (AS3 unsigned int*)l, 16, 0, 17);
}

// ---------------- fused f32 -> fp16 conversion (facts, Wr, W, mem_old) ----------
__global__ void cvt_all(const float4* __restrict__ sf, ushort4* __restrict__ df,
                        const float4* __restrict__ s1, ushort4* __restrict__ d1,
                        const float4* __restrict__ s2, ushort4* __restrict__ d2,
                        const float4* __restrict__ sm, ushort4* __restrict__ dm) {
  int i = blockIdx.x * blockDim.x + threadIdx.x;
  int st = gridDim.x * blockDim.x;
  for (int k = i; k < 4751360; k += st) {
    const float4* s; ushort4* d; int off;
    if (k < 4194304)      { s = sf; d = df; off = k; }
    else if (k < 4456448) { s = s1; d = d1; off = k - 4194304; }
    else if (k < 4718592) { s = s2; d = d2; off = k - 4456448; }
    else                  { s = sm; d = dm; off = k - 4718592; }
    float4 v = s[off];
    ushort4 o;
    o.x = f32_f16(v.x); o.y = f32_f16(v.y); o.z = f32_f16(v.z); o.w = f32_f16(v.w);
    d[off] = o;
  }
}

// ---------------- phase 1: C[t][b][0:2048] = facts(b,t,:) @ [Wr|W]^T (fp16 out) ----
// BK=64 (16 K-tiles), XOR source-swizzle staging: LDS pos p of row r holds
// source chunk p^(r&7) -> ds_read_b128 fragments spread over all 32 banks.
__global__ __launch_bounds__(256, 2) void gemm_fw(
    const unsigned short* __restrict__ A,
    const unsigned short* __restrict__ Bt,
    unsigned short* __restrict__ Ct)
{
  __shared__ __align__(16) unsigned short As[128 * 64];
  __shared__ __align__(16) unsigned short Bs[128 * 64];
  const int tid = threadIdx.x;
  const int lane = tid & 63;
  const int wv = tid >> 6;
  const int q = lane >> 4, ln = lane & 15;
  const int bm = blockIdx.x, bn = blockIdx.y;
  const int wm = (wv >> 1) * 64, wn = (wv & 1) * 64;

  f32x4 acc[4][4] = {};

  for (int kt = 0; kt < 1024; kt += 64) {
    __syncthreads();
#pragma unroll
    for (int rr = 0; rr < 4; ++rr) {
      int chunk = rr * 256 + tid;          // 0..1023
      int r = chunk >> 3, c = chunk & 7;   // 8 chunks (16B) per 128B row
      int cs = c ^ (r & 7);                // source chunk for this LDS pos
      gl_lds16(A + (size_t)(bm * 128 + r) * 1024 + kt + cs * 8, As + chunk * 8);
      gl_lds16(Bt + (size_t)(bn * 128 + r) * 1024 + kt + cs * 8, Bs + chunk * 8);
    }
    __syncthreads();
    f16x8 af[4][2], bfr[4][2];
#pragma unroll
    for (int mi = 0; mi < 4; ++mi)
#pragma unroll
      for (int kk = 0; kk < 2; ++kk)
        af[mi][kk] = *(const f16x8*)(As + (wm + mi * 16 + ln) * 64 + (((q + 4 * kk) ^ (ln & 7)) * 8));
#pragma unroll
    for (int ni = 0; ni < 4; ++ni)
#pragma unroll
      for (int kk = 0; kk < 2; ++kk)
        bfr[ni][kk] = *(const f16x8*)(Bs + (wn + ni * 16 + ln) * 64 + (((q + 4 * kk) ^ (ln & 7)) * 8));
#pragma unroll
    for (int kk = 0; kk < 2; ++kk)
#pragma unroll
      for (int mi = 0; mi < 4; ++mi)
#pragma unroll
        for (int ni = 0; ni < 4; ++ni)
          acc[mi][ni] = __builtin_amdgcn_mfma_f32_16x16x32_f16(af[mi][kk], bfr[ni][kk], acc[mi][ni], 0, 0, 0);
  }
#pragma unroll
  for (int mi = 0; mi < 4; ++mi)
#pragma unroll
    for (int ni = 0; ni < 4; ++ni)
#pragma unroll
      for (int r2 = 0; r2 < 4; ++r2) {
        int trow = wm + mi * 16 + q * 4 + r2;   // == t
        int col = bn * 128 + wn + ni * 16 + ln; // 0..2047: [fWr | fW]
        Ct[(size_t)trow * 262144 + (size_t)bm * 2048 + col] = f32_f16(acc[mi][ni][r2]);
      }
}

// ---------------- phase 2: the recurrence (R6-proven coherence/barrier) -------
// Grid 256 = 8 groups x 32 dim-slices; ga = blockIdx&7 (XCD-locality heuristic).
// h hand-off via Infinity Cache: relaxed agent atomic u32 write-through stores,
// staging reads bypass L1+L2 (aux=17). Per-block flag lines 128B apart; tid0
// release after full-block barrier; wave-0 ONLY polls 32 flags (minimum
// pollers per flag line — R8 showed 4-wave polling costs ~1 µs/step).
__global__ __launch_bounds__(256, 2) void gru_recur(
    const unsigned short* __restrict__ fwx,   // [128 t][128 b][2048] f16
    const float* __restrict__ Urw, const float* __restrict__ Urb,
    const float* __restrict__ Uw,  const float* __restrict__ Ub,
    const float* __restrict__ g,              // [128 b][128 t]
    const float* __restrict__ mem_old,        // [128][1024]
    const int* __restrict__ nfp,              // [128]
    unsigned short* __restrict__ hbf,         // [2][128][1024] f16
    unsigned int* __restrict__ flg,           // [8 ga][32 blk][32 pad] u32
    float* __restrict__ out)                  // [128][1024] f32
{
  __shared__ __align__(16) unsigned char At[32768]; // 16 rows x 2048B, dense
  __shared__ float xchg[512];

  const int tid = threadIdx.x;
  const int lane = tid & 63;
  const int w = tid >> 6;
  const int q = lane >> 4;
  const int ln = lane & 15;
  const int matrix = w >> 1;
  const int ntile = w & 1;
  const int ga = blockIdx.x & 7;    // XCD-local group under round-robin dispatch
  const int dsl = blockIdx.x >> 3;  // dim-slice within group
  const int b0 = ga * 16;
  const int n_g = dsl * 32 + ntile * 16 + ln;

  // --- one-time: weights into registers (B-fragment layout: n=lane&15, k=q*8+j) ---
  const float* Wm = matrix ? Uw : Urw;
  f16x8 bw[32];
#pragma unroll
  for (int ks = 0; ks < 32; ++ks) {
    const float* s = Wm + (size_t)n_g * 1024 + ks * 32 + q * 8;
    float4 x0 = *(const float4*)s;
    float4 x1 = *(const float4*)(s + 4);
    f16x8 t;
    t[0] = (_Float16)x0.x; t[1] = (_Float16)x0.y;
    t[2] = (_Float16)x0.z; t[3] = (_Float16)x0.w;
    t[4] = (_Float16)x1.x; t[5] = (_Float16)x1.y;
    t[6] = (_Float16)x1.z; t[7] = (_Float16)x1.w;
    bw[ks] = t;
  }
  const float bias = (matrix ? Ub : Urb)[n_g];
  f32x4 acc = {bias, bias, bias, bias};

  float h_own[4] = {0.f, 0.f, 0.f, 0.f};
  int nf[4] = {0, 0, 0, 0};
  if (matrix == 0) {
#pragma unroll
    for (int r = 0; r < 4; ++r) {
      int b = b0 + q * 4 + r;
      h_own[r] = mem_old[(size_t)b * 1024 + n_g];
      nf[r] = nfp[b];
    }
  }

  // A-fragment read bases: row ln, chunk(ks) = (q + 4*ks) ^ (ln&7).
  const int swz = ln & 7;
  const int rowb = ln * 2048 + (q ^ (swz & 3)) * 16;
  const int be = rowb + ((swz >> 2) << 6);        // ks even
  const int bo = rowb + (((swz >> 2) ^ 1) << 6);  // ks odd

  for (int t = 0; t < 128; ++t) {
    // stage h(t) group tile (16 x 1024 f16 = 32KB), coherent (IC) reads
    const unsigned short* hsrc = hbf + (size_t)(t & 1) * 131072 + (size_t)b0 * 1024;
#pragma unroll
    for (int j = 0; j < 8; ++j) {
      int blk = w * 8 + j;
      int m = blk >> 1, kh = blk & 1;
      gl_lds16_coh(hsrc + m * 1024 + kh * 512 + ((lane ^ (m & 7)) * 8),
                   (unsigned short*)(At + m * 2048 + kh * 1024));
    }
    __syncthreads(); // drains vmcnt -> staging complete

    // epilogue operands: issue early, consumed after MFMA loop (plain cached loads)
    float fwrv[4], fwv[4], gv[4];
    if (matrix == 0) {
#pragma unroll
      for (int r = 0; r < 4; ++r) {
        int b = b0 + q * 4 + r;
        size_t base = (size_t)t * 262144 + (size_t)b * 2048;
        fwrv[r] = f16_f32(fwx[base + n_g]);
        fwv[r]  = f16_f32(fwx[base + 1024 + n_g]);
        gv[r]   = g[b * 128 + t];
      }
    }

#pragma unroll
    for (int ks = 0; ks < 32; ++ks) {
      const unsigned char* ap = At + (((ks & 1) ? bo : be) + ((ks >> 1) << 7));
      f16x8 a = *(const f16x8*)ap;
      acc = __builtin_amdgcn_mfma_f32_16x16x32_f16(a, bw[ks], acc, 0, 0, 0);
    }

    if (matrix == 1) { // u = U h + U_b -> exchange to r-side waves
#pragma unroll
      for (int r = 0; r < 4; ++r)
        xchg[ntile * 256 + (q * 4 + r) * 16 + ln] = acc[r];
    }
    __syncthreads();
    if (matrix == 0) {
      unsigned int* hb32 = (unsigned int*)(hbf + (size_t)((t + 1) & 1) * 131072);
#pragma unroll
      for (int r = 0; r < 4; ++r) {
        float u = xchg[ntile * 256 + (q * 4 + r) * 16 + ln];
        float rg = 1.0f / (1.0f + __expf(-(acc[r] + fwrv[r])));
        float pre = fwv[r] + rg * u;
        float e2 = __expf(-2.0f * fabsf(pre));
        float th = (1.0f - e2) / (1.0f + e2);
        float ht = copysignf(th, pre);
        float hn = gv[r] * ht + (1.0f - gv[r]) * h_own[r];
        h_own[r] = hn;
        int b = b0 + q * 4 + r;
        // pack adjacent dims (n_g even|odd) into u32, write-through to IC
        unsigned short hu = f32_f16(hn);
        unsigned short pu = (unsigned short)__shfl_xor((int)hu, 1, 64);
        if (!(ln & 1))
          __hip_atomic_store(&hb32[(b * 1024 + n_g) >> 1],
                             (unsigned)hu | ((unsigned)pu << 16),
                             __ATOMIC_RELAXED, __HIP_MEMORY_SCOPE_AGENT);
        if (t == nf[r] - 1) out[(size_t)b * 1024 + n_g] = hn;
      }
    }
    acc[0] = bias; acc[1] = bias; acc[2] = bias; acc[3] = bias;

    __syncthreads(); // vmcnt(0): h write-through stores IC-acked before release
    if (t < 127) {
      if (tid == 0)
        __hip_atomic_store(&flg[(ga * 32 + dsl) * 32], (unsigned)(t + 1),
                           __ATOMIC_RELAXED, __HIP_MEMORY_SCOPE_AGENT);
      if (w == 0) {
        unsigned int* fp = &flg[(ga * 32 + (lane & 31)) * 32];
        for (;;) {
          unsigned v = __hip_atomic_load(fp, __ATOMIC_RELAXED, __HIP_MEMORY_SCOPE_AGENT);
          if (__ballot(lane < 32 && v < (unsigned)(t + 1)) == 0ull) break;
        }
      }
      __syncthreads();
    }
  }
}

extern "C" void kernel_launch(void* const* d_in, const int* in_sizes, int n_in,
                              void* d_out, int out_size, void* d_ws, size_t ws_size,
                              hipStream_t stream) {
  const float* facts     = (const float*)d_in[0]; // [128][128][1024]
  const int*   num_facts = (const int*)d_in[1];   // [128]
  const float* g         = (const float*)d_in[2]; // [128][128][1]
  const float* mem_old   = (const float*)d_in[3]; // [128][1][1024]
  const float* Wr        = (const float*)d_in[4]; // [1024][1024]
  const float* Urw       = (const float*)d_in[5];
  const float* Urb       = (const float*)d_in[6];
  const float* W         = (const float*)d_in[7];
  const float* Uw        = (const float*)d_in[8];
  const float* Ub        = (const float*)d_in[9];

  // workspace layout (f16 elements unless noted)
  unsigned short* facts_h = (unsigned short*)d_ws;        // 16,777,216
  unsigned short* wstack  = facts_h + 16777216;           //  2,097,152 ([Wr|W])
  unsigned short* fwx     = wstack + 2097152;             // 33,554,432 ([t][b][2048])
  unsigned short* hbf     = fwx + 33554432;               //    262,144 (2 x [128][1024])
  unsigned int*   flg     = (unsigned int*)(hbf + 262144);// 8*32*32 u32 = 32KB
  float* out = (float*)d_out;

  hipMemsetAsync(flg, 0, 8 * 32 * 32 * 4, stream);
  cvt_all<<<4096, 256, 0, stream>>>(
      (const float4*)facts,   (ushort4*)facts_h,
      (const float4*)Wr,      (ushort4*)wstack,
      (const float4*)W,       (ushort4*)(wstack + 1048576),
      (const float4*)mem_old, (ushort4*)hbf);
  gemm_fw<<<dim3(128, 16), 256, 0, stream>>>(facts_h, wstack, fwx);
  gru_recur<<<256, 256, 0, stream>>>(fwx, Urw, Urb, Uw, Ub, g, mem_old, num_facts, hbf, flg, out);
}